// Round 6
// baseline (653.771 us; speedup 1.0000x reference)
//
#include <hip/hip_runtime.h>
#include <math.h>

// BVP Helmholtz-residual PINN via MFMA, round 12.
// Rounds 8-11 ledger: MfmaUtil ~43-45% invariant to TLP (8 vs 16 waves/CU),
// LDS traffic (x0.5 in r11, bank-conflict counter halved, perf unchanged),
// and prefetch depth (r9). Per-batch budget: MFMA 17.4K + VALU 7.3K +
// LDS 10.7K + A-L2 9.4K cy ~= the 40.5K wall -> pipes run ~serially;
// the barrier-alternating phase structure is the bottleneck, not any pipe.
// Round-12: megakernel alternation. Each block pipelines GPB=8 groups of
// 16 points: P1 = fused GEMM {L2(g) || L3(g-1)} - every wave issues 224
// MFMAs, all 8 waves at once (2x phase density, no r8 starvation);
// P2 = jets {jet2(g), jet3(g-1)}; P3 = out(g-1) + layer1(g+1). 3 barriers
// per group (vs ~5). acc2/acc3 live within one iteration only (no r7
// rolled-loop spill trap). B1/B2 single-buffered: every LDS hazard edge
// has >=1 barrier (checked). launch_bounds(512,1): LDS caps occupancy at
// 2 waves/SIMD regardless, so no register cap -> no spill risk.

typedef __attribute__((ext_vector_type(8))) short short8;
typedef __attribute__((ext_vector_type(4))) float floatx4;
typedef unsigned short ushort_t;
typedef unsigned int uint_t;

#define GPB 8            // point-groups per block
#define PBLK (16 * GPB)  // 128 points per block

__device__ __forceinline__ ushort_t f2bf(float f) {
    uint_t u = __float_as_uint(f);
    return (ushort_t)((u + 0x7FFFu + ((u >> 16) & 1u)) >> 16);  // RNE
}
// pack2bf(f0,f1): {bf16(f0), bf16(f1)} in one u32 (f0 low). Round-half-up.
__device__ __forceinline__ uint_t pack2bf(float f0, float f1) {
    uint_t u0 = __float_as_uint(f0) + 0x8000u;
    uint_t u1 = __float_as_uint(f1) + 0x8000u;
    return __builtin_amdgcn_perm(u1, u0, 0x07060302u);
}
__device__ __forceinline__ float fast_tanh(float u) {
    float e = __expf(2.f * u);
    return 1.f - 2.f / (e + 1.f);   // exact at +-inf for finite u
}

// ws: 2 layers x 16 row-tiles x 8 kc x 64 lanes x 16B = 256 KB.
// A-frag lane (m=lane&15, qa=lane>>4) slot j:
//   layer0 (W2, natural):  col = kc*32 + 8*qa + j
//   layer1 (W3, permuted): col = kc*32 + 16*(j>>2) + 4*qa + (j&3)
__global__ void prep_split(const float* __restrict__ W2, const float* __restrict__ W3,
                           short8* __restrict__ ws) {
    int t16 = blockIdx.x * blockDim.x + threadIdx.x;  // 0..16383
    int lane = t16 & 63;
    int kc = (t16 >> 6) & 7;
    int tt = (t16 >> 9) & 15;
    int l = t16 >> 13;
    const float* W = l ? W3 : W2;
    int row = tt * 16 + (lane & 15);
    int qa = lane >> 4;
    const float* src = W + row * 256 + kc * 32 + (l ? 4 * qa : 8 * qa);
    float4 va = *(const float4*)src;
    float4 vb = *(const float4*)(src + (l ? 16 : 4));
    float v[8] = {va.x, va.y, va.z, va.w, vb.x, vb.y, vb.z, vb.w};
    short8 hi8;
    #pragma unroll
    for (int j = 0; j < 8; ++j) hi8[j] = (short)f2bf(v[j]);   // RNE (runs once)
    ws[l * 8192 + tt * 512 + kc * 64 + lane] = hi8;
}

__global__ __launch_bounds__(512, 1)
void bvp_main(const float* __restrict__ gx, const float* __restrict__ gy,
              const float* __restrict__ gz, const float* __restrict__ gf,
              const float* __restrict__ W1, const float* __restrict__ b1,
              const float* __restrict__ b2, const float* __restrict__ b3,
              const float* __restrict__ W4, const float* __restrict__ b4,
              const short8* __restrict__ wsA, float* __restrict__ out, int N) {
    __shared__ short8 B1sh[7 * 8 * 64];   // 57344 B: layer-2 input jets
    __shared__ short8 B2sh[7 * 8 * 64];   // 57344 B: layer-3 input jets
    __shared__ float red[8][16][8];       // 4 KB cross-wave reduction scratch

    const int tid = threadIdx.x;
    const int w = tid >> 6, lane = tid & 63;
    const int n15 = lane & 15, qc = lane >> 4;
    const int blockbase = blockIdx.x * PBLK;
    const short8* __restrict__ wsA3 = wsA + 8192;

    floatx4 acc2[2][7];   // layer-2 accum, group g
    floatx4 acc3[2][7];   // layer-3 accum, group g-1
    short8 a2c[2], a3c[2];  // kc=0 A fragments, preloaded a phase early

    // ---- layer 1 (VALU) -> B1 fragments; coords passed in preloaded ----
    auto stage_l1 = [&](float xi, float yi, float zi, float fi) {
        const int pp = tid & 15, u8g = tid >> 4;   // u8g 0..31: neurons 8*u8g..+7
        float hv[7][8];
        #pragma unroll
        for (int r = 0; r < 8; ++r) {
            const int i = u8g * 8 + r;
            float4 wv = *(const float4*)(W1 + 4 * i);
            float u = fmaf(wv.x, xi, fmaf(wv.y, yi, fmaf(wv.z, zi, fmaf(wv.w, fi, b1[i]))));
            float t = fast_tanh(u), s = 1.f - t * t, c = -2.f * t * s;
            hv[0][r] = t;
            hv[1][r] = s * wv.x; hv[2][r] = s * wv.y; hv[3][r] = s * wv.z;
            hv[4][r] = c * wv.x * wv.x; hv[5][r] = c * wv.y * wv.y; hv[6][r] = c * wv.z * wv.z;
        }
        const int kt = u8g >> 2, qb = u8g & 3;     // k-slot qb*8+r (natural order)
        #pragma unroll
        for (int s = 0; s < 7; ++s) {
            union { short8 s8; uint_t u4[4]; } v;
            #pragma unroll
            for (int j = 0; j < 4; ++j)
                v.u4[j] = pack2bf(hv[s][2 * j], hv[s][2 * j + 1]);
            B1sh[(s * 8 + kt) * 64 + qb * 16 + pp] = v.s8;
        }
    };

    // ---- preload kc=0 A fragments for the NEXT GEMM phase ----
    auto load_a0 = [&]() {
        #pragma unroll
        for (int rt = 0; rt < 2; ++rt) a2c[rt] = wsA[(2 * w + rt) * 512 + lane];
        #pragma unroll
        for (int rt = 0; rt < 2; ++rt) a3c[rt] = wsA3[(2 * w + rt) * 512 + lane];
    };

    // ---- single-layer GEMM (pipeline peels) ----
    auto gemm_one = [&](const short8* __restrict__ A, const short8* __restrict__ Bs,
                        floatx4 (&acc)[2][7], short8 (&ac)[2]) {
        #pragma unroll
        for (int rt = 0; rt < 2; ++rt)
            #pragma unroll
            for (int ct = 0; ct < 7; ++ct) acc[rt][ct] = (floatx4){0.f, 0.f, 0.f, 0.f};
        short8 a0[2] = {ac[0], ac[1]}, a1[2];
        #pragma unroll
        for (int kc = 0; kc < 8; ++kc) {
            if (kc < 7) {
                #pragma unroll
                for (int rt = 0; rt < 2; ++rt)
                    a1[rt] = A[(2 * w + rt) * 512 + (kc + 1) * 64 + lane];
            }
            short8 b[7];
            #pragma unroll
            for (int ct = 0; ct < 7; ++ct) b[ct] = Bs[(ct * 8 + kc) * 64 + lane];
            #pragma unroll
            for (int ct = 0; ct < 7; ++ct)
                #pragma unroll
                for (int rt = 0; rt < 2; ++rt)
                    acc[rt][ct] = __builtin_amdgcn_mfma_f32_16x16x32_bf16(a0[rt], b[ct], acc[rt][ct], 0, 0, 0);
            if (kc < 7) {
                #pragma unroll
                for (int rt = 0; rt < 2; ++rt) a0[rt] = a1[rt];
            }
        }
    };

    // ---- fused GEMM: layer-2(group g) + layer-3(group g-1), 28 MFMA/kc ----
    auto gemm_fused = [&]() {
        #pragma unroll
        for (int rt = 0; rt < 2; ++rt)
            #pragma unroll
            for (int ct = 0; ct < 7; ++ct) {
                acc2[rt][ct] = (floatx4){0.f, 0.f, 0.f, 0.f};
                acc3[rt][ct] = (floatx4){0.f, 0.f, 0.f, 0.f};
            }
        short8 a20[2] = {a2c[0], a2c[1]}, a30[2] = {a3c[0], a3c[1]};
        short8 a21[2], a31[2];
        #pragma unroll
        for (int kc = 0; kc < 8; ++kc) {
            if (kc < 7) {
                #pragma unroll
                for (int rt = 0; rt < 2; ++rt) {
                    a21[rt] = wsA[(2 * w + rt) * 512 + (kc + 1) * 64 + lane];
                    a31[rt] = wsA3[(2 * w + rt) * 512 + (kc + 1) * 64 + lane];
                }
            }
            short8 b1f[7];
            #pragma unroll
            for (int ct = 0; ct < 7; ++ct) b1f[ct] = B1sh[(ct * 8 + kc) * 64 + lane];
            #pragma unroll
            for (int ct = 0; ct < 7; ++ct)
                #pragma unroll
                for (int rt = 0; rt < 2; ++rt)
                    acc2[rt][ct] = __builtin_amdgcn_mfma_f32_16x16x32_bf16(a20[rt], b1f[ct], acc2[rt][ct], 0, 0, 0);
            short8 b2f[7];
            #pragma unroll
            for (int ct = 0; ct < 7; ++ct) b2f[ct] = B2sh[(ct * 8 + kc) * 64 + lane];
            #pragma unroll
            for (int ct = 0; ct < 7; ++ct)
                #pragma unroll
                for (int rt = 0; rt < 2; ++rt)
                    acc3[rt][ct] = __builtin_amdgcn_mfma_f32_16x16x32_bf16(a30[rt], b2f[ct], acc3[rt][ct], 0, 0, 0);
            if (kc < 7) {
                #pragma unroll
                for (int rt = 0; rt < 2; ++rt) { a20[rt] = a21[rt]; a30[rt] = a31[rt]; }
            }
        }
    };

    // ---- jet 2 (lane-local): acc2 -> B2 fragments ----
    // Wave w's 32 rows are exactly k-tile w; permuted k-order
    // k(qc,j)=16(j>>2)+4qc+(j&3) makes the repack lane-local.
    auto jet2 = [&]() {
        #pragma unroll
        for (int rt = 0; rt < 2; ++rt) {
            const float4 bb = *(const float4*)(b2 + w * 32 + rt * 16 + qc * 4);
            const float bbv[4] = {bb.x, bb.y, bb.z, bb.w};
            #pragma unroll
            for (int r = 0; r < 4; ++r) {
                float t = fast_tanh(acc2[rt][0][r] + bbv[r]);
                float s = 1.f - t * t, c = -2.f * t * s;
                float ux = acc2[rt][1][r], uy = acc2[rt][2][r], uz = acc2[rt][3][r];
                acc2[rt][0][r] = t;
                acc2[rt][1][r] = s * ux; acc2[rt][2][r] = s * uy; acc2[rt][3][r] = s * uz;
                acc2[rt][4][r] = fmaf(s, acc2[rt][4][r], c * ux * ux);
                acc2[rt][5][r] = fmaf(s, acc2[rt][5][r], c * uy * uy);
                acc2[rt][6][r] = fmaf(s, acc2[rt][6][r], c * uz * uz);
            }
        }
        #pragma unroll
        for (int s = 0; s < 7; ++s) {
            union { short8 s8; uint_t u4[4]; } v;
            v.u4[0] = pack2bf(acc2[0][s][0], acc2[0][s][1]);
            v.u4[1] = pack2bf(acc2[0][s][2], acc2[0][s][3]);
            v.u4[2] = pack2bf(acc2[1][s][0], acc2[1][s][1]);
            v.u4[3] = pack2bf(acc2[1][s][2], acc2[1][s][3]);
            B2sh[(s * 8 + w) * 64 + lane] = v.s8;   // kt = w, own lane slot
        }
    };

    // ---- jet 3 + layer-4 partials (lane-local): acc3 -> red ----
    auto jet3red = [&]() {
        float pt[8] = {0.f, 0.f, 0.f, 0.f, 0.f, 0.f, 0.f, 0.f};
        #pragma unroll
        for (int rt = 0; rt < 2; ++rt) {
            const int rb = w * 32 + rt * 16 + qc * 4;
            const float4 bb = *(const float4*)(b3 + rb);
            const float4 w0 = *(const float4*)(W4 + rb);
            const float4 w1 = *(const float4*)(W4 + 256 + rb);
            const float bbv[4] = {bb.x, bb.y, bb.z, bb.w};
            const float w0v[4] = {w0.x, w0.y, w0.z, w0.w};
            const float w1v[4] = {w1.x, w1.y, w1.z, w1.w};
            #pragma unroll
            for (int r = 0; r < 4; ++r) {
                float t = fast_tanh(acc3[rt][0][r] + bbv[r]);
                float s = 1.f - t * t, c = -2.f * t * s;
                float ux = acc3[rt][1][r], uy = acc3[rt][2][r], uz = acc3[rt][3][r];
                float hv = t;
                float hxx = fmaf(s, acc3[rt][4][r], c * ux * ux);
                float hyy = fmaf(s, acc3[rt][5][r], c * uy * uy);
                float hzz = fmaf(s, acc3[rt][6][r], c * uz * uz);
                pt[0] = fmaf(w0v[r], hv, pt[0]);
                pt[1] = fmaf(w0v[r], hxx, pt[1]);
                pt[2] = fmaf(w0v[r], hyy, pt[2]);
                pt[3] = fmaf(w0v[r], hzz, pt[3]);
                pt[4] = fmaf(w1v[r], hv, pt[4]);
                pt[5] = fmaf(w1v[r], hxx, pt[5]);
                pt[6] = fmaf(w1v[r], hyy, pt[6]);
                pt[7] = fmaf(w1v[r], hzz, pt[7]);
            }
        }
        #pragma unroll
        for (int k = 0; k < 8; ++k) {
            pt[k] += __shfl_xor(pt[k], 16, 64);
            pt[k] += __shfl_xor(pt[k], 32, 64);
        }
        if (qc == 0) {
            *(float4*)&red[w][n15][0] = make_float4(pt[0], pt[1], pt[2], pt[3]);
            *(float4*)&red[w][n15][4] = make_float4(pt[4], pt[5], pt[6], pt[7]);
        }
    };

    // ---- final cross-wave reduction + Helmholtz residual for group @ gb ----
    auto finalout = [&](int gb) {
        if (tid < 16 && (gb + tid) < N) {
            const int n = gb + tid;
            float s8[8] = {0.f, 0.f, 0.f, 0.f, 0.f, 0.f, 0.f, 0.f};
            #pragma unroll
            for (int ww = 0; ww < 8; ++ww)
                #pragma unroll
                for (int k = 0; k < 8; ++k) s8[k] += red[ww][tid][k];
            const float fi = gf[n];
            const float PI = 3.14159265358979323846f;
            const float kw = 2.f * PI * (fi * 500.f + 100.f) / 343.f;
            const float vol = 0.7f * 0.5f * 0.6f;
            const float kk = vol * vol * kw * kw;
            const float cxx = (0.5f * 0.6f) * (0.5f * 0.6f);
            const float cyy = (0.7f * 0.6f) * (0.7f * 0.6f);
            const float czz = (0.7f * 0.5f) * (0.7f * 0.5f);
            const float pr = s8[0] + b4[0];
            const float pim = s8[4] + b4[1];
            out[n]     = 2.0f * (cxx * s8[1] + cyy * s8[2] + czz * s8[3]) + kk * (pr * 2.0f + 0.1f);
            out[N + n] = 1.5f * (cxx * s8[5] + cyy * s8[6] + czz * s8[7]) + kk * (pim * 1.5f - 0.05f);
        }
    };

    // ================= pipeline =================
    // Prologue: L1(g0); a2c for first GEMM issued under L1 math.
    {
        const int p0 = min(blockbase + (tid & 15), N - 1);
        #pragma unroll
        for (int rt = 0; rt < 2; ++rt) a2c[rt] = wsA[(2 * w + rt) * 512 + lane];
        stage_l1(gx[p0], gy[p0], gz[p0], gf[p0]);
    }
    __syncthreads();

    // iter 0 peel: GEMM2(g0) | jet2(g0) | L1(g1)
    {
        const int p1i = min(blockbase + 16 + (tid & 15), N - 1);
        const float x1 = gx[p1i], y1 = gy[p1i], z1 = gz[p1i], f1 = gf[p1i];
        gemm_one(wsA, B1sh, acc2, a2c);
        __syncthreads();
        load_a0();
        jet2();
        __syncthreads();
        stage_l1(x1, y1, z1, f1);
        __syncthreads();
    }

    // middle iters: P1 fusedGEMM | P2 jets | P3 out + L1(next)
    #pragma unroll 1
    for (int i = 1; i < GPB; ++i) {
        const int pn = min(blockbase + (i + 1) * 16 + (tid & 15), N - 1);
        const float xn = gx[pn], yn = gy[pn], zn = gz[pn], fn = gf[pn];
        gemm_fused();
        __syncthreads();
        load_a0();
        jet2();
        jet3red();
        __syncthreads();
        finalout(blockbase + (i - 1) * 16);
        if (i < GPB - 1) stage_l1(xn, yn, zn, fn);
        __syncthreads();
    }

    // epilogue: GEMM3(g_{GPB-1}) | jet3 | out
    gemm_one(wsA3, B2sh, acc3, a3c);
    jet3red();
    __syncthreads();
    finalout(blockbase + (GPB - 1) * 16);
}

extern "C" void kernel_launch(void* const* d_in, const int* in_sizes, int n_in,
                              void* d_out, int out_size, void* d_ws, size_t ws_size,
                              hipStream_t stream) {
    const float* x = (const float*)d_in[0];
    const float* y = (const float*)d_in[1];
    const float* z = (const float*)d_in[2];
    const float* f = (const float*)d_in[3];
    const float* W1 = (const float*)d_in[4];
    const float* b1 = (const float*)d_in[5];
    const float* W2 = (const float*)d_in[6];
    const float* b2 = (const float*)d_in[7];
    const float* W3 = (const float*)d_in[8];
    const float* b3 = (const float*)d_in[9];
    const float* W4 = (const float*)d_in[10];
    const float* b4 = (const float*)d_in[11];
    float* out = (float*)d_out;
    const int N = in_sizes[0];
    const int grid = (N + PBLK - 1) / PBLK;

    prep_split<<<64, 256, 0, stream>>>(W2, W3, (short8*)d_ws);
    bvp_main<<<grid, 512, 0, stream>>>(x, y, z, f, W1, b1, b2, b3, W4, b4,
                                       (const short8*)d_ws, out, N);
}

// Round 7
// 265.371 us; speedup vs baseline: 2.4636x; 2.4636x over previous
//
#include <hip/hip_runtime.h>
#include <math.h>

// BVP Helmholtz-residual PINN via MFMA, round 13.
// Rounds 7-12 ledger: every schedule rearrangement spills (r7,r12: second
// acc set / rolled-loop live ranges -> GB-scale scratch), starves the MFMA
// pipe (r8 lockstep: 2 waves/SIMD issue -> 36%), or is neutral (r9 B-ring,
// r11 B-reuse x4 with bank-conflict counter halved). MfmaUtil ~43-45%
// invariant to TLP/LDS/prefetch. The schedule is not the lever.
// Round-13: ALGORITHMIC cut - 7 jet streams -> 5. The residual only uses
// the weighted Laplacian L = cxx*p_xx + cyy*p_yy + czz*p_zz (same weights
// re/im). tanh jet: h_ii = s*u_ii + c*u_i^2, so the weighted sum
// propagates closed-form: L_h = s*L_u + c*(cxx*ux^2+cyy*uy^2+czz*uz^2) -
// needs first derivs (carried anyway), not individual second derivs.
// Streams {v,dx,dy,dz,L}: MFMA 1792->1280/block, LDS/VALU/reduction x5/7.
// Exact same fp32 math (linearity); structure = round-6 champion verbatim.

typedef __attribute__((ext_vector_type(8))) short short8;
typedef __attribute__((ext_vector_type(4))) float floatx4;
typedef unsigned short ushort_t;
typedef unsigned int uint_t;

#define PBLK 16
#define NS 5   // jet streams: 0=v 1=dx 2=dy 3=dz 4=weighted-Laplacian

#define CXX 0.09f     // (YC*ZC)^2 = (0.5*0.6)^2
#define CYY 0.1764f   // (XC*ZC)^2 = (0.7*0.6)^2
#define CZZ 0.1225f   // (XC*YC)^2 = (0.7*0.5)^2

__device__ __forceinline__ ushort_t f2bf(float f) {
    uint_t u = __float_as_uint(f);
    return (ushort_t)((u + 0x7FFFu + ((u >> 16) & 1u)) >> 16);  // RNE
}
// pack2bf(f0,f1): {bf16(f0), bf16(f1)} in one u32 (f0 low). Round-half-up.
__device__ __forceinline__ uint_t pack2bf(float f0, float f1) {
    uint_t u0 = __float_as_uint(f0) + 0x8000u;
    uint_t u1 = __float_as_uint(f1) + 0x8000u;
    return __builtin_amdgcn_perm(u1, u0, 0x07060302u);
}
__device__ __forceinline__ float fast_tanh(float u) {
    float e = __expf(2.f * u);
    return 1.f - 2.f / (e + 1.f);   // exact at +-inf for finite u
}

// ws: 2 layers x 16 row-tiles x 8 kc x 64 lanes x 16B = 256 KB.
// A-frag lane (m=lane&15, qa=lane>>4) slot j:
//   layer0 (W2, natural):  col = kc*32 + 8*qa + j
//   layer1 (W3, permuted): col = kc*32 + 16*(j>>2) + 4*qa + (j&3)
__global__ void prep_split(const float* __restrict__ W2, const float* __restrict__ W3,
                           short8* __restrict__ ws) {
    int t16 = blockIdx.x * blockDim.x + threadIdx.x;  // 0..16383
    int lane = t16 & 63;
    int kc = (t16 >> 6) & 7;
    int tt = (t16 >> 9) & 15;
    int l = t16 >> 13;
    const float* W = l ? W3 : W2;
    int row = tt * 16 + (lane & 15);
    int qa = lane >> 4;
    const float* src = W + row * 256 + kc * 32 + (l ? 4 * qa : 8 * qa);
    float4 va = *(const float4*)src;
    float4 vb = *(const float4*)(src + (l ? 16 : 4));
    float v[8] = {va.x, va.y, va.z, va.w, vb.x, vb.y, vb.z, vb.w};
    short8 hi8;
    #pragma unroll
    for (int j = 0; j < 8; ++j) hi8[j] = (short)f2bf(v[j]);   // RNE (runs once)
    ws[l * 8192 + tt * 512 + kc * 64 + lane] = hi8;
}

__global__ __launch_bounds__(512, 4)
void bvp_main(const float* __restrict__ gx, const float* __restrict__ gy,
              const float* __restrict__ gz, const float* __restrict__ gf,
              const float* __restrict__ W1, const float* __restrict__ b1,
              const float* __restrict__ b2, const float* __restrict__ b3,
              const float* __restrict__ W4, const float* __restrict__ b4,
              const short8* __restrict__ wsA, float* __restrict__ out, int N) {
    __shared__ short8 Bsh[NS * 8 * 64];  // 40960 B: B[s][kt][lane]
    __shared__ float red[8][16][4];      // 2 KB cross-wave reduction scratch

    const int tid = threadIdx.x;
    const int w = tid >> 6, lane = tid & 63;
    const int n15 = lane & 15, qc = lane >> 4;
    const int pbase = blockIdx.x * PBLK;
    const short8* __restrict__ wsA3 = wsA + 8192;

    floatx4 acc[2][NS];  // 2 row-tiles (32 rows) x 5 streams
    short8 a0[2], a1[2];

    // GEMM-2 A(kc=0): issue now, covered by layer-1 math.
    #pragma unroll
    for (int rt = 0; rt < 2; ++rt) a0[rt] = wsA[(2 * w + rt) * 512 + lane];

    // ---------------- layer 1 (VALU) -> B fragments ----------------
    // pp = tid&15: 16-lane groups write contiguous 256B -> conflict-free;
    // threads sharing u8 read the same W1 rows (broadcast).
    // u linear in x,y,z -> L_u = 0, so L_h = c*(cxx*wx^2+cyy*wy^2+czz*wz^2).
    {
        const int pp = tid & 15, u8 = tid >> 4;     // u8 in 0..31: neurons 8*u8..+7
        const int pidx = min(pbase + pp, N - 1);
        const float xi = gx[pidx], yi = gy[pidx], zi = gz[pidx], fi = gf[pidx];
        float hv[NS][8];
        #pragma unroll
        for (int r = 0; r < 8; ++r) {
            const int i = u8 * 8 + r;
            float4 wv = *(const float4*)(W1 + 4 * i);
            float u = fmaf(wv.x, xi, fmaf(wv.y, yi, fmaf(wv.z, zi, fmaf(wv.w, fi, b1[i]))));
            float t = fast_tanh(u), s = 1.f - t * t, c = -2.f * t * s;
            float wq = fmaf(CXX * wv.x, wv.x, fmaf(CYY * wv.y, wv.y, CZZ * wv.z * wv.z));
            hv[0][r] = t;
            hv[1][r] = s * wv.x; hv[2][r] = s * wv.y; hv[3][r] = s * wv.z;
            hv[4][r] = c * wq;
        }
        const int kt = u8 >> 2, qb = u8 & 3;        // k-slot qb*8+r (natural order)
        #pragma unroll
        for (int s = 0; s < NS; ++s) {
            union { short8 s8; uint_t u4[4]; } v;
            #pragma unroll
            for (int j = 0; j < 4; ++j)
                v.u4[j] = pack2bf(hv[s][2 * j], hv[s][2 * j + 1]);
            Bsh[(s * 8 + kt) * 64 + qb * 16 + pp] = v.s8;
        }
    }
    __syncthreads();

    // K-loop: A 1-deep global prefetch (L2-resident), B single-buffer LDS.
    auto run_gemm = [&](const short8* __restrict__ A) {
        #pragma unroll
        for (int rt = 0; rt < 2; ++rt)
            #pragma unroll
            for (int ct = 0; ct < NS; ++ct) acc[rt][ct] = (floatx4){0.f, 0.f, 0.f, 0.f};
        #pragma unroll
        for (int kc = 0; kc < 8; ++kc) {
            if (kc < 7) {
                #pragma unroll
                for (int rt = 0; rt < 2; ++rt)
                    a1[rt] = A[(2 * w + rt) * 512 + (kc + 1) * 64 + lane];
            }
            short8 b[NS];
            #pragma unroll
            for (int ct = 0; ct < NS; ++ct) b[ct] = Bsh[(ct * 8 + kc) * 64 + lane];
            #pragma unroll
            for (int ct = 0; ct < NS; ++ct)
                #pragma unroll
                for (int rt = 0; rt < 2; ++rt)
                    acc[rt][ct] = __builtin_amdgcn_mfma_f32_16x16x32_bf16(a0[rt], b[ct], acc[rt][ct], 0, 0, 0);
            if (kc < 7) {
                #pragma unroll
                for (int rt = 0; rt < 2; ++rt) a0[rt] = a1[rt];
            }
        }
    };

    // ---------------- GEMM 2 ----------------
    run_gemm(wsA);
    __syncthreads();   // all waves done reading layer-2 B

    // GEMM-3 A(kc=0): issue now, covered by jet-2 math.
    #pragma unroll
    for (int rt = 0; rt < 2; ++rt) a0[rt] = wsA3[(2 * w + rt) * 512 + lane];

    // ---------------- jet 2 (lane-local) -> new B fragments ----------------
    // Wave w's 32 rows are exactly k-tile w; permuted k-order
    // k(qc,j)=16(j>>2)+4qc+(j&3) makes the repack lane-local.
    // L-stream: L_h = s*L_u + c*(cxx*ux^2 + cyy*uy^2 + czz*uz^2).
    #pragma unroll
    for (int rt = 0; rt < 2; ++rt) {
        const float4 bb = *(const float4*)(b2 + w * 32 + rt * 16 + qc * 4);
        const float bbv[4] = {bb.x, bb.y, bb.z, bb.w};
        #pragma unroll
        for (int r = 0; r < 4; ++r) {
            float t = fast_tanh(acc[rt][0][r] + bbv[r]);
            float s = 1.f - t * t, c = -2.f * t * s;
            float ux = acc[rt][1][r], uy = acc[rt][2][r], uz = acc[rt][3][r];
            float wq = fmaf(CXX * ux, ux, fmaf(CYY * uy, uy, CZZ * uz * uz));
            acc[rt][0][r] = t;
            acc[rt][1][r] = s * ux; acc[rt][2][r] = s * uy; acc[rt][3][r] = s * uz;
            acc[rt][4][r] = fmaf(s, acc[rt][4][r], c * wq);
        }
    }
    #pragma unroll
    for (int s = 0; s < NS; ++s) {
        union { short8 s8; uint_t u4[4]; } v;
        v.u4[0] = pack2bf(acc[0][s][0], acc[0][s][1]);
        v.u4[1] = pack2bf(acc[0][s][2], acc[0][s][3]);
        v.u4[2] = pack2bf(acc[1][s][0], acc[1][s][1]);
        v.u4[3] = pack2bf(acc[1][s][2], acc[1][s][3]);
        Bsh[(s * 8 + w) * 64 + lane] = v.s8;   // kt = w, own lane slot
    }
    __syncthreads();

    // ---------------- GEMM 3 ----------------
    run_gemm(wsA3);

    // ---------------- jet 3 + layer-4 partials (lane-local) ----------------
    // Layer-4 is linear: needs only value and L streams.
    float pt[4] = {0.f, 0.f, 0.f, 0.f};
    #pragma unroll
    for (int rt = 0; rt < 2; ++rt) {
        const int rb = w * 32 + rt * 16 + qc * 4;
        const float4 bb = *(const float4*)(b3 + rb);
        const float4 w0 = *(const float4*)(W4 + rb);
        const float4 w1 = *(const float4*)(W4 + 256 + rb);
        const float bbv[4] = {bb.x, bb.y, bb.z, bb.w};
        const float w0v[4] = {w0.x, w0.y, w0.z, w0.w};
        const float w1v[4] = {w1.x, w1.y, w1.z, w1.w};
        #pragma unroll
        for (int r = 0; r < 4; ++r) {
            float t = fast_tanh(acc[rt][0][r] + bbv[r]);
            float s = 1.f - t * t, c = -2.f * t * s;
            float ux = acc[rt][1][r], uy = acc[rt][2][r], uz = acc[rt][3][r];
            float wq = fmaf(CXX * ux, ux, fmaf(CYY * uy, uy, CZZ * uz * uz));
            float hL = fmaf(s, acc[rt][4][r], c * wq);
            pt[0] = fmaf(w0v[r], t, pt[0]);
            pt[1] = fmaf(w0v[r], hL, pt[1]);
            pt[2] = fmaf(w1v[r], t, pt[2]);
            pt[3] = fmaf(w1v[r], hL, pt[3]);
        }
    }
    #pragma unroll
    for (int k = 0; k < 4; ++k) {
        pt[k] += __shfl_xor(pt[k], 16, 64);
        pt[k] += __shfl_xor(pt[k], 32, 64);
    }
    if (qc == 0)
        *(float4*)&red[w][n15][0] = make_float4(pt[0], pt[1], pt[2], pt[3]);
    __syncthreads();

    if (tid < 16 && (pbase + tid) < N) {
        const int n = pbase + tid;
        float s4[4] = {0.f, 0.f, 0.f, 0.f};
        #pragma unroll
        for (int ww = 0; ww < 8; ++ww)
            #pragma unroll
            for (int k = 0; k < 4; ++k) s4[k] += red[ww][tid][k];
        const float fi = gf[n];
        const float PI = 3.14159265358979323846f;
        const float kw = 2.f * PI * (fi * 500.f + 100.f) / 343.f;
        const float vol = 0.7f * 0.5f * 0.6f;
        const float kk = vol * vol * kw * kw;
        const float pr = s4[0] + b4[0];
        const float pim = s4[2] + b4[1];
        out[n]     = 2.0f * s4[1] + kk * (pr * 2.0f + 0.1f);
        out[N + n] = 1.5f * s4[3] + kk * (pim * 1.5f - 0.05f);
    }
}

extern "C" void kernel_launch(void* const* d_in, const int* in_sizes, int n_in,
                              void* d_out, int out_size, void* d_ws, size_t ws_size,
                              hipStream_t stream) {
    const float* x = (const float*)d_in[0];
    const float* y = (const float*)d_in[1];
    const float* z = (const float*)d_in[2];
    const float* f = (const float*)d_in[3];
    const float* W1 = (const float*)d_in[4];
    const float* b1 = (const float*)d_in[5];
    const float* W2 = (const float*)d_in[6];
    const float* b2 = (const float*)d_in[7];
    const float* W3 = (const float*)d_in[8];
    const float* b3 = (const float*)d_in[9];
    const float* W4 = (const float*)d_in[10];
    const float* b4 = (const float*)d_in[11];
    float* out = (float*)d_out;
    const int N = in_sizes[0];
    const int grid = (N + PBLK - 1) / PBLK;

    prep_split<<<64, 256, 0, stream>>>(W2, W3, (short8*)d_ws);
    bvp_main<<<grid, 512, 0, stream>>>(x, y, z, f, W1, b1, b2, b3, W4, b4,
                                       (const short8*)d_ws, out, N);
}

// Round 8
// 265.362 us; speedup vs baseline: 2.4637x; 1.0000x over previous
//
#include <hip/hip_runtime.h>
#include <math.h>

// BVP Helmholtz-residual PINN via MFMA, round 14.
// Round-13 (NS=5 streams) WIN: 256 -> 210 us; MFMA time scaled x5/7 exactly.
// New budget per 2-block batch: MFMA 12.4K cy, VALU 9.9K, LDS pipe ~17K ->
// at NS=5 with only x2 B-reuse the CU-wide LDS pipe EXCEEDS MFMA demand.
// Round-11's B-reuse-x4 was neutral because at NS=7 it also halved waves/CU
// (confound). At NS=5 LDS/block = 43008 B -> THREE blocks/CU fit (129K),
// restoring 12 waves/CU while halving LDS reads.
// Round-14: 256 thr (4 waves) x 4 row-tiles/wave, NS=5, 3 blocks/CU.
// Per 3-block round: MFMA 18.6K > LDS 11.5K (reads hide under MFMA even
// in-phase: per kc/SIMD 180 cy LDS vs 1164 cy MFMA) -> LDS off the
// critical path. acc[4][5]=80 +a0/a1 32 +b 20 ~ 150 regs; launch_bounds
// (256,3) caps 168 (512/SIMD pool /3), 12x168=2016<=2048.

typedef __attribute__((ext_vector_type(8))) short short8;
typedef __attribute__((ext_vector_type(4))) float floatx4;
typedef unsigned short ushort_t;
typedef unsigned int uint_t;

#define PBLK 16
#define NS 5   // jet streams: 0=v 1=dx 2=dy 3=dz 4=weighted-Laplacian

#define CXX 0.09f     // (YC*ZC)^2 = (0.5*0.6)^2
#define CYY 0.1764f   // (XC*ZC)^2 = (0.7*0.6)^2
#define CZZ 0.1225f   // (XC*YC)^2 = (0.7*0.5)^2

__device__ __forceinline__ ushort_t f2bf(float f) {
    uint_t u = __float_as_uint(f);
    return (ushort_t)((u + 0x7FFFu + ((u >> 16) & 1u)) >> 16);  // RNE
}
// pack2bf(f0,f1): {bf16(f0), bf16(f1)} in one u32 (f0 low). Round-half-up.
__device__ __forceinline__ uint_t pack2bf(float f0, float f1) {
    uint_t u0 = __float_as_uint(f0) + 0x8000u;
    uint_t u1 = __float_as_uint(f1) + 0x8000u;
    return __builtin_amdgcn_perm(u1, u0, 0x07060302u);
}
__device__ __forceinline__ float fast_tanh(float u) {
    float e = __expf(2.f * u);
    return 1.f - 2.f / (e + 1.f);   // exact at +-inf for finite u
}

// ws: 2 layers x 16 row-tiles x 8 kc x 64 lanes x 16B = 256 KB.
// A-frag lane (m=lane&15, qa=lane>>4) slot j:
//   layer0 (W2, natural):  col = kc*32 + 8*qa + j
//   layer1 (W3, permuted): col = kc*32 + 16*(j>>2) + 4*qa + (j&3)
__global__ void prep_split(const float* __restrict__ W2, const float* __restrict__ W3,
                           short8* __restrict__ ws) {
    int t16 = blockIdx.x * blockDim.x + threadIdx.x;  // 0..16383
    int lane = t16 & 63;
    int kc = (t16 >> 6) & 7;
    int tt = (t16 >> 9) & 15;
    int l = t16 >> 13;
    const float* W = l ? W3 : W2;
    int row = tt * 16 + (lane & 15);
    int qa = lane >> 4;
    const float* src = W + row * 256 + kc * 32 + (l ? 4 * qa : 8 * qa);
    float4 va = *(const float4*)src;
    float4 vb = *(const float4*)(src + (l ? 16 : 4));
    float v[8] = {va.x, va.y, va.z, va.w, vb.x, vb.y, vb.z, vb.w};
    short8 hi8;
    #pragma unroll
    for (int j = 0; j < 8; ++j) hi8[j] = (short)f2bf(v[j]);   // RNE (runs once)
    ws[l * 8192 + tt * 512 + kc * 64 + lane] = hi8;
}

__global__ __launch_bounds__(256, 3)
void bvp_main(const float* __restrict__ gx, const float* __restrict__ gy,
              const float* __restrict__ gz, const float* __restrict__ gf,
              const float* __restrict__ W1, const float* __restrict__ b1,
              const float* __restrict__ b2, const float* __restrict__ b3,
              const float* __restrict__ W4, const float* __restrict__ b4,
              const short8* __restrict__ wsA, float* __restrict__ out, int N) {
    __shared__ short8 Bsh[NS * 8 * 64];  // 40960 B: B[s][kt][lane]
    __shared__ float red[4][16][4];      // 1 KB cross-wave reduction scratch

    const int tid = threadIdx.x;
    const int w = tid >> 6, lane = tid & 63;   // w in 0..3
    const int n15 = lane & 15, qc = lane >> 4;
    const int pbase = blockIdx.x * PBLK;
    const short8* __restrict__ wsA3 = wsA + 8192;

    floatx4 acc[4][NS];  // 4 row-tiles (64 rows) x 5 streams = 80 VGPR
    short8 a0[4], a1[4];

    // GEMM-2 A(kc=0): issue now, covered by layer-1 math.
    #pragma unroll
    for (int rt = 0; rt < 4; ++rt) a0[rt] = wsA[(4 * w + rt) * 512 + lane];

    // ---------------- layer 1 (VALU) -> B fragments ----------------
    // pp = tid&15: 16-lane groups write contiguous 256B -> conflict-free;
    // 256 threads: each handles two u8 neuron-groups sequentially.
    // u linear in x,y,z -> L_u = 0, so L_h = c*(cxx*wx^2+cyy*wy^2+czz*wz^2).
    {
        const int pp = tid & 15;
        const int pidx = min(pbase + pp, N - 1);
        const float xi = gx[pidx], yi = gy[pidx], zi = gz[pidx], fi = gf[pidx];
        #pragma unroll
        for (int g = 0; g < 2; ++g) {
            const int u8 = (tid >> 4) + 16 * g;   // 0..31: neurons 8*u8..+7
            float hv[NS][8];
            #pragma unroll
            for (int r = 0; r < 8; ++r) {
                const int i = u8 * 8 + r;
                float4 wv = *(const float4*)(W1 + 4 * i);
                float u = fmaf(wv.x, xi, fmaf(wv.y, yi, fmaf(wv.z, zi, fmaf(wv.w, fi, b1[i]))));
                float t = fast_tanh(u), s = 1.f - t * t, c = -2.f * t * s;
                float wq = fmaf(CXX * wv.x, wv.x, fmaf(CYY * wv.y, wv.y, CZZ * wv.z * wv.z));
                hv[0][r] = t;
                hv[1][r] = s * wv.x; hv[2][r] = s * wv.y; hv[3][r] = s * wv.z;
                hv[4][r] = c * wq;
            }
            const int kt = u8 >> 2, qb = u8 & 3;  // k-slot qb*8+r (natural order)
            #pragma unroll
            for (int s = 0; s < NS; ++s) {
                union { short8 s8; uint_t u4[4]; } v;
                #pragma unroll
                for (int j = 0; j < 4; ++j)
                    v.u4[j] = pack2bf(hv[s][2 * j], hv[s][2 * j + 1]);
                Bsh[(s * 8 + kt) * 64 + qb * 16 + pp] = v.s8;
            }
        }
    }
    __syncthreads();

    // K-loop: A 1-deep global prefetch (L2-resident), B single-buffer LDS.
    // One ds_read_b128 feeds 4 MFMAs (rt reuse x4).
    auto run_gemm = [&](const short8* __restrict__ A) {
        #pragma unroll
        for (int rt = 0; rt < 4; ++rt)
            #pragma unroll
            for (int ct = 0; ct < NS; ++ct) acc[rt][ct] = (floatx4){0.f, 0.f, 0.f, 0.f};
        #pragma unroll
        for (int kc = 0; kc < 8; ++kc) {
            if (kc < 7) {
                #pragma unroll
                for (int rt = 0; rt < 4; ++rt)
                    a1[rt] = A[(4 * w + rt) * 512 + (kc + 1) * 64 + lane];
            }
            short8 b[NS];
            #pragma unroll
            for (int ct = 0; ct < NS; ++ct) b[ct] = Bsh[(ct * 8 + kc) * 64 + lane];
            #pragma unroll
            for (int ct = 0; ct < NS; ++ct)
                #pragma unroll
                for (int rt = 0; rt < 4; ++rt)
                    acc[rt][ct] = __builtin_amdgcn_mfma_f32_16x16x32_bf16(a0[rt], b[ct], acc[rt][ct], 0, 0, 0);
            if (kc < 7) {
                #pragma unroll
                for (int rt = 0; rt < 4; ++rt) a0[rt] = a1[rt];
            }
        }
    };

    // ---------------- GEMM 2 ----------------
    run_gemm(wsA);
    __syncthreads();   // all waves done reading layer-2 B

    // GEMM-3 A(kc=0): issue now, covered by jet-2 math.
    #pragma unroll
    for (int rt = 0; rt < 4; ++rt) a0[rt] = wsA3[(4 * w + rt) * 512 + lane];

    // ---------------- jet 2 (lane-local) -> new B fragments ----------------
    // Wave w's 64 rows are k-tiles 2w,2w+1; permuted k-order
    // k(qc,j)=16(j>>2)+4qc+(j&3): slot j=(rt&1)*4+r, tile kt2=rt>>1.
    // L-stream: L_h = s*L_u + c*(cxx*ux^2 + cyy*uy^2 + czz*uz^2).
    #pragma unroll
    for (int rt = 0; rt < 4; ++rt) {
        const float4 bb = *(const float4*)(b2 + w * 64 + rt * 16 + qc * 4);
        const float bbv[4] = {bb.x, bb.y, bb.z, bb.w};
        #pragma unroll
        for (int r = 0; r < 4; ++r) {
            float t = fast_tanh(acc[rt][0][r] + bbv[r]);
            float s = 1.f - t * t, c = -2.f * t * s;
            float ux = acc[rt][1][r], uy = acc[rt][2][r], uz = acc[rt][3][r];
            float wq = fmaf(CXX * ux, ux, fmaf(CYY * uy, uy, CZZ * uz * uz));
            acc[rt][0][r] = t;
            acc[rt][1][r] = s * ux; acc[rt][2][r] = s * uy; acc[rt][3][r] = s * uz;
            acc[rt][4][r] = fmaf(s, acc[rt][4][r], c * wq);
        }
    }
    #pragma unroll
    for (int s = 0; s < NS; ++s)
        #pragma unroll
        for (int kt2 = 0; kt2 < 2; ++kt2) {
            union { short8 s8; uint_t u4[4]; } v;
            v.u4[0] = pack2bf(acc[2 * kt2][s][0], acc[2 * kt2][s][1]);
            v.u4[1] = pack2bf(acc[2 * kt2][s][2], acc[2 * kt2][s][3]);
            v.u4[2] = pack2bf(acc[2 * kt2 + 1][s][0], acc[2 * kt2 + 1][s][1]);
            v.u4[3] = pack2bf(acc[2 * kt2 + 1][s][2], acc[2 * kt2 + 1][s][3]);
            Bsh[(s * 8 + 2 * w + kt2) * 64 + lane] = v.s8;   // own lane slot
        }
    __syncthreads();

    // ---------------- GEMM 3 ----------------
    run_gemm(wsA3);

    // ---------------- jet 3 + layer-4 partials (lane-local) ----------------
    // Layer-4 is linear: needs only value and L streams.
    float pt[4] = {0.f, 0.f, 0.f, 0.f};
    #pragma unroll
    for (int rt = 0; rt < 4; ++rt) {
        const int rb = w * 64 + rt * 16 + qc * 4;
        const float4 bb = *(const float4*)(b3 + rb);
        const float4 w0 = *(const float4*)(W4 + rb);
        const float4 w1 = *(const float4*)(W4 + 256 + rb);
        const float bbv[4] = {bb.x, bb.y, bb.z, bb.w};
        const float w0v[4] = {w0.x, w0.y, w0.z, w0.w};
        const float w1v[4] = {w1.x, w1.y, w1.z, w1.w};
        #pragma unroll
        for (int r = 0; r < 4; ++r) {
            float t = fast_tanh(acc[rt][0][r] + bbv[r]);
            float s = 1.f - t * t, c = -2.f * t * s;
            float ux = acc[rt][1][r], uy = acc[rt][2][r], uz = acc[rt][3][r];
            float wq = fmaf(CXX * ux, ux, fmaf(CYY * uy, uy, CZZ * uz * uz));
            float hL = fmaf(s, acc[rt][4][r], c * wq);
            pt[0] = fmaf(w0v[r], t, pt[0]);
            pt[1] = fmaf(w0v[r], hL, pt[1]);
            pt[2] = fmaf(w1v[r], t, pt[2]);
            pt[3] = fmaf(w1v[r], hL, pt[3]);
        }
    }
    #pragma unroll
    for (int k = 0; k < 4; ++k) {
        pt[k] += __shfl_xor(pt[k], 16, 64);
        pt[k] += __shfl_xor(pt[k], 32, 64);
    }
    if (qc == 0)
        *(float4*)&red[w][n15][0] = make_float4(pt[0], pt[1], pt[2], pt[3]);
    __syncthreads();

    if (tid < 16 && (pbase + tid) < N) {
        const int n = pbase + tid;
        float s4[4] = {0.f, 0.f, 0.f, 0.f};
        #pragma unroll
        for (int ww = 0; ww < 4; ++ww)
            #pragma unroll
            for (int k = 0; k < 4; ++k) s4[k] += red[ww][tid][k];
        const float fi = gf[n];
        const float PI = 3.14159265358979323846f;
        const float kw = 2.f * PI * (fi * 500.f + 100.f) / 343.f;
        const float vol = 0.7f * 0.5f * 0.6f;
        const float kk = vol * vol * kw * kw;
        const float pr = s4[0] + b4[0];
        const float pim = s4[2] + b4[1];
        out[n]     = 2.0f * s4[1] + kk * (pr * 2.0f + 0.1f);
        out[N + n] = 1.5f * s4[3] + kk * (pim * 1.5f - 0.05f);
    }
}

extern "C" void kernel_launch(void* const* d_in, const int* in_sizes, int n_in,
                              void* d_out, int out_size, void* d_ws, size_t ws_size,
                              hipStream_t stream) {
    const float* x = (const float*)d_in[0];
    const float* y = (const float*)d_in[1];
    const float* z = (const float*)d_in[2];
    const float* f = (const float*)d_in[3];
    const float* W1 = (const float*)d_in[4];
    const float* b1 = (const float*)d_in[5];
    const float* W2 = (const float*)d_in[6];
    const float* b2 = (const float*)d_in[7];
    const float* W3 = (const float*)d_in[8];
    const float* b3 = (const float*)d_in[9];
    const float* W4 = (const float*)d_in[10];
    const float* b4 = (const float*)d_in[11];
    float* out = (float*)d_out;
    const int N = in_sizes[0];
    const int grid = (N + PBLK - 1) / PBLK;

    prep_split<<<64, 256, 0, stream>>>(W2, W3, (short8*)d_ws);
    bvp_main<<<grid, 256, 0, stream>>>(x, y, z, f, W1, b1, b2, b3, W4, b4,
                                       (const short8*)d_ws, out, N);
}